// Round 9
// baseline (364.655 us; speedup 1.0000x reference)
//
#include <hip/hip_runtime.h>
#include <stdint.h>
#include <stddef.h>

// ---------------------------------------------------------------------------
// QuantizedLinear: y = x @ (scale*(Wq - zp))^T + bias ; M=8192,N=4096,K=4096
// R9: 256x256 tile, BK=64, 8 waves (2Mx4N). A staged in LDS (dbuf, 64KiB,
// proven zero-conflict chunk swizzle); B fragments loaded DIRECTLY
// global->VGPR via inline-asm global_load_dwordx4 (per-lane addr == MFMA
// B-frag layout; B is L2/L3-resident, L1 dedups the 2-waves/block reuse).
// Cuts LDS port demand ~40% (8 ds_reads + half the DMA writes per tile
// removed) so DS drains fully under the MFMA windows.
// Per tile: 4 phases, 1 barrier, counted vmcnt/lgkm, setprio clusters.
// ---------------------------------------------------------------------------

typedef __attribute__((ext_vector_type(4))) float   f32x4;
typedef __attribute__((ext_vector_type(8))) short   short8;   // 8 x bf16
typedef __attribute__((ext_vector_type(4))) int     i32x4;
typedef __attribute__((ext_vector_type(8))) unsigned short ushort8;
typedef __attribute__((ext_vector_type(4))) unsigned short ushort4v;

__device__ __forceinline__ unsigned short f2bf(float f) {
  union { float f; unsigned u; } v; v.f = f;
  unsigned u = v.u;
  u += 0x7fffu + ((u >> 16) & 1u);      // RNE to bf16
  return (unsigned short)(u >> 16);
}

__device__ __forceinline__ void gld_lds16(const void* g, void* l) {
  __builtin_amdgcn_global_load_lds(
      (const __attribute__((address_space(1))) unsigned int*)g,
      (__attribute__((address_space(3))) unsigned int*)l,
      16, 0, 0);
}

__device__ __forceinline__ unsigned ldsAddr(const void* p) {
  return (unsigned)(size_t)(const __attribute__((address_space(3))) void*)p;
}

__device__ __forceinline__ void wgb() {
  asm volatile("" ::: "memory");
  __builtin_amdgcn_s_barrier();
  asm volatile("" ::: "memory");
}

#define DSR(dst, addr, OFF) \
  asm volatile("ds_read_b128 %0, %1 offset:" #OFF : "=v"(dst) : "v"(addr))
#define LGKM(N) do { asm volatile("s_waitcnt lgkmcnt(" #N ")" ::: "memory"); \
                     __builtin_amdgcn_sched_barrier(0); } while (0)
#define VMCNT(N) do { asm volatile("s_waitcnt vmcnt(" #N ")" ::: "memory"); \
                      __builtin_amdgcn_sched_barrier(0); } while (0)
// B direct load: OFF is a string byte-offset literal ("0" for kh0, "64" for kh1)
#define BL1(R, P, OFF) \
  asm volatile("global_load_dwordx4 %0, %1, off offset:" OFF : "=v"(R) : "v"(P))
#define BLOAD(DST, OFF) do { BL1(DST[0], bp0, OFF); BL1(DST[1], bp1, OFF); \
                             BL1(DST[2], bp2, OFF); BL1(DST[3], bp3, OFF); } while (0)

// ---------- prepass: x fp32 -> bf16 ----------
__global__ __launch_bounds__(256) void cvt_x_kernel(
    const f32x4* __restrict__ x, ushort8* __restrict__ o, int n8) {
  int i = blockIdx.x * 256 + threadIdx.x;
  if (i >= n8) return;
  f32x4 a = x[2 * i], b = x[2 * i + 1];
  ushort8 r;
  r[0] = f2bf(a[0]); r[1] = f2bf(a[1]); r[2] = f2bf(a[2]); r[3] = f2bf(a[3]);
  r[4] = f2bf(b[0]); r[5] = f2bf(b[1]); r[6] = f2bf(b[2]); r[7] = f2bf(b[3]);
  o[i] = r;
}

// ---------- prepass: Wq int32 -> bf16 of (q - zp) ----------
__global__ __launch_bounds__(256) void cvt_w_kernel(
    const i32x4* __restrict__ q, ushort8* __restrict__ o,
    const float* __restrict__ zp_p, int n8) {
  int i = blockIdx.x * 256 + threadIdx.x;
  if (i >= n8) return;
  float zp = zp_p[0];
  i32x4 a = q[2 * i], b = q[2 * i + 1];
  ushort8 r;
  r[0] = f2bf((float)a[0] - zp); r[1] = f2bf((float)a[1] - zp);
  r[2] = f2bf((float)a[2] - zp); r[3] = f2bf((float)a[3] - zp);
  r[4] = f2bf((float)b[0] - zp); r[5] = f2bf((float)b[1] - zp);
  r[6] = f2bf((float)b[2] - zp); r[7] = f2bf((float)b[3] - zp);
  o[i] = r;
}

// ---------------------------------------------------------------------------
// Main 256^2 GEMM: A via LDS (dbuf x 2kh regions of [256 rows][32 k], 16KiB,
// chunk swizzle c ^= (r>>1)&3 both-sides), B via direct global->reg.
// ---------------------------------------------------------------------------
__global__ __launch_bounds__(512, 2) void qgemm256_kernel(
    const unsigned short* __restrict__ A,   // [M][K] bf16 (x)
    const unsigned short* __restrict__ B,   // [N][K] bf16 (dequant W)
    const float* __restrict__ bias, const float* __restrict__ scale_p,
    float* __restrict__ C, int M, int N, int K) {
  __shared__ __attribute__((aligned(16))) unsigned short sA[2 * 2 * 8192]; // 64KiB

  const int tid  = threadIdx.x;
  const int lane = tid & 63;
  const int w    = tid >> 6;         // 0..7
  const int wr   = w >> 2;           // 0..1  (M strip of 128)
  const int wc   = w & 3;            // 0..3  (N strip of 64)

  // XCD-aware block swizzle (bijective when nwg % 8 == 0)
  const int nwg = gridDim.x;
  const int bid = blockIdx.x;
  const int swz = ((nwg & 7) == 0) ? ((bid & 7) * (nwg >> 3) + (bid >> 3)) : bid;
  const int ntn = N >> 8;
  const int bm0 = (swz / ntn) << 8;
  const int bn0 = (swz % ntn) << 8;

  const int l16 = lane & 15;
  const int l4  = lane >> 4;                       // 0..3 -> k chunk
  const int rchk = (l4 ^ ((l16 >> 1) & 3)) << 4;   // swizzled chunk byte off

  const unsigned aBase = (unsigned)((wr * 128 + l16) * 64 + rchk);
  const unsigned sAaddr = ldsAddr(sA);

  // A staging: thread covers rows (tid>>2), (tid>>2)+128; one 16B chunk each
  const int    st0  = tid, st1 = tid + 512;
  const size_t rK0  = (size_t)(tid >> 2) * K;
  const size_t rK1  = (size_t)((tid >> 2) + 128) * K;
  const int    csrc = ((tid & 3) ^ ((tid >> 3) & 3)) << 3;

  const unsigned short* Ab = A + (size_t)bm0 * K;

  // B per-lane fragment pointers (advance +64 elems per K-tile)
  const unsigned short* bp0 = B + (size_t)(bn0 + wc * 64 + l16) * K + (l4 << 3);
  const unsigned short* bp1 = bp0 + (size_t)16 * K;
  const unsigned short* bp2 = bp0 + (size_t)32 * K;
  const unsigned short* bp3 = bp0 + (size_t)48 * K;

  f32x4 acc[8][4] = {};
  const int nkt = K >> 6;

#define STAGE_A(T) do {                                               \
    const int _nx = (T) & 1; const int _k = (T) << 6;                 \
    unsigned short* _d0 = sA + (((_nx << 1) + 0) << 13);              \
    unsigned short* _d1 = sA + (((_nx << 1) + 1) << 13);              \
    gld_lds16(Ab + rK0 + _k + csrc,      _d0 + (st0 << 3));           \
    gld_lds16(Ab + rK1 + _k + csrc,      _d0 + (st1 << 3));           \
    gld_lds16(Ab + rK0 + _k + 32 + csrc, _d1 + (st0 << 3));           \
    gld_lds16(Ab + rK1 + _k + 32 + csrc, _d1 + (st1 << 3));           \
  } while (0)

#define ISSUE_ALO(AS, RG) do {                                        \
    unsigned _a = sAaddr + ((unsigned)(RG) << 14) + aBase;            \
    DSR(AS[0], _a, 0); DSR(AS[1], _a, 1024);                          \
    DSR(AS[2], _a, 2048); DSR(AS[3], _a, 3072);                       \
  } while (0)
#define ISSUE_AHI(RG) do {                                            \
    unsigned _a = sAaddr + ((unsigned)(RG) << 14) + aBase;            \
    DSR(a2[0], _a, 4096); DSR(a2[1], _a, 5120);                       \
    DSR(a2[2], _a, 6144); DSR(a2[3], _a, 7168);                       \
  } while (0)

#define MMLO(AS, BS) do { __builtin_amdgcn_s_setprio(1);                       \
    _Pragma("unroll") for (int m = 0; m < 4; ++m)                              \
    _Pragma("unroll") for (int n = 0; n < 4; ++n)                              \
      acc[m][n] = __builtin_amdgcn_mfma_f32_16x16x32_bf16(AS[m], BS[n], acc[m][n], 0, 0, 0); \
    __builtin_amdgcn_s_setprio(0); } while (0)
#define MMHI(BS) do { __builtin_amdgcn_s_setprio(1);                           \
    _Pragma("unroll") for (int m = 0; m < 4; ++m)                              \
    _Pragma("unroll") for (int n = 0; n < 4; ++n)                              \
      acc[4 + m][n] = __builtin_amdgcn_mfma_f32_16x16x32_bf16(a2[m], BS[n], acc[4 + m][n], 0, 0, 0); \
    __builtin_amdgcn_s_setprio(0); } while (0)

  short8 aX[4], aY[4], a2[4], b0v[4], b1v[4];

  // ---- prologue: stage A(0); load B(0,kh0); A(0,kh0,lo) to regs ----
  STAGE_A(0);
  BLOAD(b0v, "0");
  VMCNT(4);                       // A stage done (b0 in flight)
  wgb();
  ISSUE_ALO(aX, 0);

  for (int kt = 0; kt < nkt; ++kt) {
    const int cur = kt & 1;
    const int rg0 = cur << 1, rg1 = rg0 + 1;
    const int nrg0 = (cur ^ 1) << 1;
    const bool pf = (kt + 1 < nkt);

    // ---- P0: a_hi(kh0) reads; B(kh1) load; MFMA lo(kh0) ----
    ISSUE_AHI(rg0);
    BLOAD(b1v, "64");
    bp0 += 64; bp1 += 64; bp2 += 64; bp3 += 64;   // advance to tile kt+1
    VMCNT(4);                     // b0 resident (b1 in flight)
    LGKM(4);                      // aX resident (a2 in flight)
    MMLO(aX, b0v);

    // ---- P1: a_lo(kh1) reads; stage A(t+1); MFMA hi(kh0) ----
    ISSUE_ALO(aY, rg1);
    if (pf) STAGE_A(kt + 1);
    LGKM(4);                      // a2 resident (aY in flight)
    MMHI(b0v);

    // ---- P2: a_hi(kh1) reads; B(t+1,kh0) load; MFMA lo(kh1) ----
    ISSUE_AHI(rg1);
    if (pf) { BLOAD(b0v, "0"); VMCNT(8); }   // b1 resident (Astage+b0 in flight)
    else    { VMCNT(0); }
    LGKM(4);                      // aY resident (a2 in flight)
    MMLO(aY, b1v);

    // ---- P3: tile boundary; MFMA hi(kh1) ----
    LGKM(0);                      // a2 resident; all own ds reads done
    if (pf) {
      VMCNT(4);                   // A stage(t+1) done for this wave (b0 in flight)
      wgb();                      // all waves' stage visible
      ISSUE_ALO(aX, nrg0);        // prefetch (t+1, kh0, lo) across the MFMA
    }
    MMHI(b1v);
  }
#undef MMHI
#undef MMLO
#undef ISSUE_AHI
#undef ISSUE_ALO
#undef STAGE_A

  // ---- epilogue: y = scale*acc + bias ----
  const float s = scale_p[0];
#pragma unroll
  for (int nf = 0; nf < 4; ++nf) {
    const int col = bn0 + wc * 64 + nf * 16 + l16;
    const float bv = bias[col];
#pragma unroll
    for (int mf = 0; mf < 8; ++mf) {
      const int row0 = bm0 + wr * 128 + mf * 16 + (l4 << 2);
#pragma unroll
      for (int j = 0; j < 4; ++j)
        C[(size_t)(row0 + j) * N + col] = fmaf(s, acc[mf][nf][j], bv);
    }
  }
}

// ---------------------------------------------------------------------------
// Fallback (no workspace): R1's fused 128^2 kernel.
// ---------------------------------------------------------------------------
__global__ __launch_bounds__(256) void qgemm_fused_kernel(
    const float* __restrict__ A, const int* __restrict__ B,
    const float* __restrict__ bias, const float* __restrict__ scale_p,
    const float* __restrict__ zp_p, float* __restrict__ C,
    int M, int N, int K) {
  constexpr int BK = 32;
  __shared__ unsigned short sAf[128 * BK];
  __shared__ unsigned short sBf[128 * BK];
  const int tid = threadIdx.x, lane = tid & 63, w = tid >> 6;
  const int wr = w >> 1, wc = w & 1;
  const int bm0 = blockIdx.y * 128, bn0 = blockIdx.x * 128;
  const int l16 = lane & 15, lk = (lane >> 4) << 3;
  const float zp = zp_p[0];
  f32x4 acc[4][4] = {};
  for (int k0 = 0; k0 < K; k0 += BK) {
#pragma unroll
    for (int c = 0; c < 4; ++c) {
      int ch = c * 256 + tid;
      int row = ch >> 3, c4 = (ch & 7) << 2;
      f32x4 av = *(const f32x4*)(A + (size_t)(bm0 + row) * K + k0 + c4);
      i32x4 bv = *(const i32x4*)(B + (size_t)(bn0 + row) * K + k0 + c4);
      ushort4v ra, rb;
      ra[0] = f2bf(av[0]); ra[1] = f2bf(av[1]); ra[2] = f2bf(av[2]); ra[3] = f2bf(av[3]);
      rb[0] = f2bf((float)bv[0] - zp); rb[1] = f2bf((float)bv[1] - zp);
      rb[2] = f2bf((float)bv[2] - zp); rb[3] = f2bf((float)bv[3] - zp);
      *(ushort4v*)&sAf[row * BK + c4] = ra;
      *(ushort4v*)&sBf[row * BK + c4] = rb;
    }
    __syncthreads();
    short8 a[4], b[4];
#pragma unroll
    for (int m = 0; m < 4; ++m) a[m] = *(const short8*)&sAf[(wr * 64 + m * 16 + l16) * BK + lk];
#pragma unroll
    for (int n = 0; n < 4; ++n) b[n] = *(const short8*)&sBf[(wc * 64 + n * 16 + l16) * BK + lk];
#pragma unroll
    for (int m = 0; m < 4; ++m)
#pragma unroll
      for (int n = 0; n < 4; ++n)
        acc[m][n] = __builtin_amdgcn_mfma_f32_16x16x32_bf16(a[m], b[n], acc[m][n], 0, 0, 0);
    __syncthreads();
  }
  const float s = scale_p[0];
#pragma unroll
  for (int n = 0; n < 4; ++n) {
    const int col = bn0 + wc * 64 + n * 16 + l16;
    const float bv = bias[col];
#pragma unroll
    for (int m = 0; m < 4; ++m) {
      const int row0 = bm0 + wr * 64 + m * 16 + ((lane >> 4) << 2);
#pragma unroll
      for (int j = 0; j < 4; ++j)
        C[(size_t)(row0 + j) * N + col] = fmaf(s, acc[m][n][j], bv);
    }
  }
}

extern "C" void kernel_launch(void* const* d_in, const int* in_sizes, int n_in,
                              void* d_out, int out_size, void* d_ws, size_t ws_size,
                              hipStream_t stream) {
  const float* x     = (const float*)d_in[0];
  const int*   wq    = (const int*)d_in[1];
  const float* bias  = (const float*)d_in[2];
  const float* scale = (const float*)d_in[3];
  const float* zp    = (const float*)d_in[4];
  float*       out   = (float*)d_out;

  const int K = 4096;
  const int N = in_sizes[1] / K;      // 4096
  const int M = in_sizes[0] / K;      // 8192

  const size_t xb_elems = (size_t)M * K;
  const size_t wb_elems = (size_t)N * K;
  const size_t need = (xb_elems + wb_elems) * sizeof(unsigned short);

  if (ws_size >= need && (M % 256 == 0) && (N % 256 == 0) && (K % 64 == 0)) {
    unsigned short* xb = (unsigned short*)d_ws;
    unsigned short* wb = xb + xb_elems;
    int nx8 = (int)(xb_elems / 8), nw8 = (int)(wb_elems / 8);
    cvt_x_kernel<<<(nx8 + 255) / 256, 256, 0, stream>>>((const f32x4*)x, (ushort8*)xb, nx8);
    cvt_w_kernel<<<(nw8 + 255) / 256, 256, 0, stream>>>((const i32x4*)wq, (ushort8*)wb, zp, nw8);
    dim3 grid((M >> 8) * (N >> 8));
    qgemm256_kernel<<<grid, 512, 0, stream>>>(xb, wb, bias, scale, out, M, N, K);
  } else {
    dim3 grid(N / 128, M / 128);
    qgemm_fused_kernel<<<grid, 256, 0, stream>>>(x, wq, bias, scale, zp, out, M, N, K);
  }
}